// Round 1
// baseline (36.006 us; speedup 1.0000x reference)
//
#include <hip/hip_runtime.h>

#define NB 32
#define NC 64
#define NO 128
#define NK 9
#define NL 4096

#define OSPLIT 8
#define OPB (NO / OSPLIT)   // 16 output channels per block
#define LTILE 1024          // 256 threads * 4 floats

// ---------- kernel 0: inv L2 norm of err_vector ----------
__global__ __launch_bounds__(256) void ev_inv_norm_kernel(
    const float* __restrict__ ev, float* __restrict__ out)
{
    float s = 0.f;
    for (int i = threadIdx.x; i < NL; i += 256) { float v = ev[i]; s += v * v; }
#pragma unroll
    for (int off = 32; off > 0; off >>= 1) s += __shfl_down(s, off, 64);
    __shared__ float red[4];
    if ((threadIdx.x & 63) == 0) red[threadIdx.x >> 6] = s;
    __syncthreads();
    if (threadIdx.x == 0) out[0] = rsqrtf(red[0] + red[1] + red[2] + red[3]);
}

// ---------- kernel 1: colsum[b][l] = sum_i x[b][i][l] ----------
__global__ __launch_bounds__(256) void colsum_kernel(
    const float* __restrict__ x, float* __restrict__ colsum)
{
    const int t4 = (blockIdx.x * 256 + threadIdx.x) * 4;   // [0, NB*NL)
    const int b = t4 / NL;
    const int l = t4 % NL;
    const float* xp = x + (size_t)b * NC * NL + l;
    float4 acc = make_float4(0.f, 0.f, 0.f, 0.f);
#pragma unroll
    for (int i = 0; i < NC; ++i) {
        float4 v = *reinterpret_cast<const float4*>(xp + (size_t)i * NL);
        acc.x += v.x; acc.y += v.y; acc.z += v.z; acc.w += v.w;
    }
    *reinterpret_cast<float4*>(colsum + t4) = acc;
}

// ---------- kernel 2: out[b,o,l] = ev_n[l] * sum_k wcn[o,k]*colsum[b,idx[k,l]] + bias[o] ----------
__global__ __launch_bounds__(256) void gmconv_main_kernel(
    const float* __restrict__ wc, const float* __restrict__ ev,
    const float* __restrict__ bias, const int* __restrict__ idx,
    const float* __restrict__ colsum, const float* __restrict__ evinv_p,
    float* __restrict__ out)
{
    __shared__ float wcn[OPB][12];   // padded rows (48B) -> 16B-aligned float4 reads
    __shared__ float biasS[OPB];

    const int bid = blockIdx.x;
    const int og = bid & (OSPLIT - 1);        // 8 o-groups
    const int lt = (bid >> 3) & 3;            // 4 l-tiles (NL / LTILE)
    const int b  = bid >> 5;                  // 32 batches
    const int t  = threadIdx.x;

    if (t < OPB) {
        const int o = og * OPB + t;
        float w[NK]; float s = 0.f;
#pragma unroll
        for (int k = 0; k < NK; ++k) { w[k] = wc[o * NK + k]; s += w[k] * w[k]; }
        const float inv = rsqrtf(s);
#pragma unroll
        for (int k = 0; k < NK; ++k) wcn[t][k] = w[k] * inv;
        wcn[t][9] = 0.f; wcn[t][10] = 0.f; wcn[t][11] = 0.f;
        biasS[t] = bias[o];
    }
    __syncthreads();

    const float evinv = evinv_p[0];
    const int l0 = lt * LTILE + t * 4;
    const float* __restrict__ cs = colsum + b * NL;

    const float4 e4 = *reinterpret_cast<const float4*>(ev + l0);
    const float ex = e4.x * evinv, ey = e4.y * evinv,
                ez = e4.z * evinv, ew = e4.w * evinv;

    // gather once per (b,l), pre-scaled by normalized err_vector
    float gx[NK], gy[NK], gz[NK], gw[NK];
#pragma unroll
    for (int k = 0; k < NK; ++k) {
        const int4 iv = *reinterpret_cast<const int4*>(idx + k * NL + l0);
        gx[k] = cs[iv.x] * ex;
        gy[k] = cs[iv.y] * ey;
        gz[k] = cs[iv.z] * ez;
        gw[k] = cs[iv.w] * ew;
    }

    float* op = out + ((size_t)b * NO + og * OPB) * NL + l0;
#pragma unroll
    for (int o = 0; o < OPB; ++o) {
        float w[12];
        *reinterpret_cast<float4*>(&w[0]) = *reinterpret_cast<const float4*>(&wcn[o][0]);
        *reinterpret_cast<float4*>(&w[4]) = *reinterpret_cast<const float4*>(&wcn[o][4]);
        *reinterpret_cast<float4*>(&w[8]) = *reinterpret_cast<const float4*>(&wcn[o][8]);
        float ax = 0.f, ay = 0.f, az = 0.f, aw = 0.f;
#pragma unroll
        for (int k = 0; k < NK; ++k) {
            ax += w[k] * gx[k];
            ay += w[k] * gy[k];
            az += w[k] * gz[k];
            aw += w[k] * gw[k];
        }
        const float bb = biasS[o];
        const float4 r = make_float4(ax + bb, ay + bb, az + bb, aw + bb);
        *reinterpret_cast<float4*>(op) = r;
        op += NL;
    }
}

extern "C" void kernel_launch(void* const* d_in, const int* in_sizes, int n_in,
                              void* d_out, int out_size, void* d_ws, size_t ws_size,
                              hipStream_t stream) {
    const float* x    = (const float*)d_in[0];   // [32,64,1,4096]
    const float* wc   = (const float*)d_in[1];   // [128,1,9]
    const float* ev   = (const float*)d_in[2];   // [1,4096]
    const float* bias = (const float*)d_in[3];   // [128]
    const int*   idx  = (const int*)d_in[4];     // [9,4096]
    float* out = (float*)d_out;                  // [32,128,1,4096]

    float* wsf    = (float*)d_ws;
    float* evinv  = wsf;          // 1 float
    float* colsum = wsf + 64;     // NB*NL floats (256B-aligned)

    hipLaunchKernelGGL(ev_inv_norm_kernel, dim3(1), dim3(256), 0, stream, ev, evinv);
    hipLaunchKernelGGL(colsum_kernel, dim3((NB * NL) / (4 * 256)), dim3(256), 0, stream,
                       x, colsum);
    hipLaunchKernelGGL(gmconv_main_kernel, dim3(NB * (NL / LTILE) * OSPLIT), dim3(256), 0,
                       stream, wc, ev, bias, idx, colsum, evinv, out);
}

// Round 3
// 25.567 us; speedup vs baseline: 1.4083x; 1.4083x over previous
//
#include <hip/hip_runtime.h>

#define NB 32
#define NC 64
#define NO 128
#define NK 9
#define NL 4096

#define OSPLIT 4
#define OPB (NO / OSPLIT)   // 32 output channels per block
#define LTILE 1024          // 256 threads * 4 floats

typedef float vfloat4 __attribute__((ext_vector_type(4)));

// ---------- kernel 1: colsum[b][l] = sum_i x[b][i][l]  (+ evinv in block 0) ----
// 256 blocks: (b, lt) with lt in [0,8) covering 512 l each.
// threads 0..127 sum channels 0..31, threads 128..255 sum channels 32..63.
__global__ __launch_bounds__(256) void colsum_kernel(
    const float* __restrict__ x, const float* __restrict__ ev,
    float* __restrict__ colsum, float* __restrict__ evinv)
{
    __shared__ vfloat4 part[128];
    __shared__ float red[4];

    const int bid = blockIdx.x;
    const int t = threadIdx.x;

    if (bid == 0) {
        // inv L2 norm of err_vector (16 KB read, L2-warm for everyone later)
        float s = 0.f;
#pragma unroll
        for (int r = 0; r < NL / 256; ++r) {
            float v = ev[r * 256 + t];
            s += v * v;
        }
#pragma unroll
        for (int off = 32; off > 0; off >>= 1) s += __shfl_down(s, off, 64);
        if ((t & 63) == 0) red[t >> 6] = s;
        __syncthreads();
        if (t == 0) evinv[0] = rsqrtf(red[0] + red[1] + red[2] + red[3]);
    }

    const int b  = bid >> 3;          // 32 batches
    const int lt = bid & 7;           // 8 tiles of 512 l
    const int col  = t & 127;         // float4 column in tile
    const int half = t >> 7;          // channel half
    const int l = lt * 512 + col * 4;

    const float* xp = x + (size_t)b * NC * NL + (size_t)half * 32 * NL + l;
    vfloat4 acc = (vfloat4){0.f, 0.f, 0.f, 0.f};
#pragma unroll
    for (int i = 0; i < 32; ++i) {
        vfloat4 v = __builtin_nontemporal_load(
            reinterpret_cast<const vfloat4*>(xp + (size_t)i * NL));
        acc += v;
    }
    if (half) part[col] = acc;
    __syncthreads();
    if (!half) {
        acc += part[col];
        *reinterpret_cast<vfloat4*>(colsum + (size_t)b * NL + l) = acc;
    }
}

// ---------- kernel 2: out[b,o,l] = evn[l] * sum_k wcn[o,k]*colsum[b,idx[k,l]] + bias[o]
__global__ __launch_bounds__(256) void gmconv_main_kernel(
    const float* __restrict__ wc, const float* __restrict__ ev,
    const float* __restrict__ bias, const int* __restrict__ idx,
    const float* __restrict__ colsum, const float* __restrict__ evinv_p,
    float* __restrict__ out)
{
    __shared__ float csS[NL];        // 16 KB staged colsum[b]
    __shared__ float wcn[OPB][12];   // padded rows -> aligned float4 reads
    __shared__ float biasS[OPB];

    const int bid = blockIdx.x;
    const int og = bid & (OSPLIT - 1);        // 4 o-groups
    const int lt = (bid >> 2) & 3;            // 4 l-tiles
    const int b  = bid >> 4;                  // 32 batches
    const int t  = threadIdx.x;

    // stage colsum[b] -> LDS (linear float4, conflict-free)
    const float* __restrict__ csg = colsum + (size_t)b * NL;
#pragma unroll
    for (int r = 0; r < NL / (4 * 256); ++r) {
        const int j = (r * 256 + t) * 4;
        *reinterpret_cast<vfloat4*>(&csS[j]) =
            *reinterpret_cast<const vfloat4*>(csg + j);
    }

    if (t < OPB) {
        const int o = og * OPB + t;
        float w[NK]; float s = 0.f;
#pragma unroll
        for (int k = 0; k < NK; ++k) { w[k] = wc[o * NK + k]; s += w[k] * w[k]; }
        const float inv = rsqrtf(s);
#pragma unroll
        for (int k = 0; k < NK; ++k) wcn[t][k] = w[k] * inv;
        wcn[t][9] = 0.f; wcn[t][10] = 0.f; wcn[t][11] = 0.f;
        biasS[t] = bias[o];
    }
    __syncthreads();

    const float evinv = evinv_p[0];
    const int l0 = lt * LTILE + t * 4;

    const vfloat4 e4 = *reinterpret_cast<const vfloat4*>(ev + l0);
    const float ex = e4.x * evinv, ey = e4.y * evinv,
                ez = e4.z * evinv, ew = e4.w * evinv;

    // gather once per (b,l) from LDS, pre-scaled by normalized err_vector
    float gx[NK], gy[NK], gz[NK], gw[NK];
#pragma unroll
    for (int k = 0; k < NK; ++k) {
        const int4 iv = *reinterpret_cast<const int4*>(idx + k * NL + l0);
        gx[k] = csS[iv.x] * ex;
        gy[k] = csS[iv.y] * ey;
        gz[k] = csS[iv.z] * ez;
        gw[k] = csS[iv.w] * ew;
    }

    float* op = out + ((size_t)b * NO + og * OPB) * NL + l0;
#pragma unroll
    for (int o = 0; o < OPB; ++o) {
        float w[12];
        *reinterpret_cast<vfloat4*>(&w[0]) = *reinterpret_cast<const vfloat4*>(&wcn[o][0]);
        *reinterpret_cast<vfloat4*>(&w[4]) = *reinterpret_cast<const vfloat4*>(&wcn[o][4]);
        *reinterpret_cast<vfloat4*>(&w[8]) = *reinterpret_cast<const vfloat4*>(&wcn[o][8]);
        float ax = 0.f, ay = 0.f, az = 0.f, aw = 0.f;
#pragma unroll
        for (int k = 0; k < NK; ++k) {
            ax += w[k] * gx[k];
            ay += w[k] * gy[k];
            az += w[k] * gz[k];
            aw += w[k] * gw[k];
        }
        const float bb = biasS[o];
        const vfloat4 r = (vfloat4){ax + bb, ay + bb, az + bb, aw + bb};
        __builtin_nontemporal_store(r, reinterpret_cast<vfloat4*>(op));
        op += NL;
    }
}

extern "C" void kernel_launch(void* const* d_in, const int* in_sizes, int n_in,
                              void* d_out, int out_size, void* d_ws, size_t ws_size,
                              hipStream_t stream) {
    const float* x    = (const float*)d_in[0];   // [32,64,1,4096]
    const float* wc   = (const float*)d_in[1];   // [128,1,9]
    const float* ev   = (const float*)d_in[2];   // [1,4096]
    const float* bias = (const float*)d_in[3];   // [128]
    const int*   idx  = (const int*)d_in[4];     // [9,4096]
    float* out = (float*)d_out;                  // [32,128,1,4096]

    float* wsf    = (float*)d_ws;
    float* evinv  = wsf;          // 1 float
    float* colsum = wsf + 64;     // NB*NL floats (256B-aligned)

    hipLaunchKernelGGL(colsum_kernel, dim3(NB * 8), dim3(256), 0, stream,
                       x, ev, colsum, evinv);
    hipLaunchKernelGGL(gmconv_main_kernel, dim3(NB * (NL / LTILE) * OSPLIT), dim3(256), 0,
                       stream, wc, ev, bias, idx, colsum, evinv, out);
}